// Round 7
// baseline (1951.534 us; speedup 1.0000x reference)
//
#include <hip/hip_runtime.h>
#include <hip/hip_bf16.h>

typedef _Float16 half8 __attribute__((ext_vector_type(8)));
typedef _Float16 half4 __attribute__((ext_vector_type(4)));
typedef float f32x4 __attribute__((ext_vector_type(4)));

// Geometry: D=256, H=8, A=64, M=400000 (64*6250), N=50000
// Algebra: out_g = sum_h (u_{g,h}/s_{g,h}) @ (Wv_h @ Wout_h) + bout
//          u_{g,h} = sum_{m in g} e_{m,h} * msg_m   (weighted row sum!)

// ---------------- wqkT: [16*64][256] f16 (q heads 0-7, k heads 8-15) ----------------
__global__ void k_convert(const float* __restrict__ Wq, const float* __restrict__ Wk,
                          _Float16* __restrict__ wqkT)
{
    int gid = blockIdx.x * 256 + threadIdx.x;   // 131072
    int h = gid >> 14;
    int d = (gid >> 6) & 255;
    int a = gid & 63;
    wqkT[((h * 64 + a) << 8) + d]       = (_Float16)Wq[gid];
    wqkT[(((8 + h) * 64 + a) << 8) + d] = (_Float16)Wk[gid];
}

// ---------------- CT[dout][h*256+din] = sum_a Wv[h][din][a]*Wout[h*64+a][dout] ----------------
__global__ void k_convC(const float* __restrict__ Wv, const float* __restrict__ Wout,
                        _Float16* __restrict__ CT)
{
    __shared__ float wv[4][64];
    int h = blockIdx.x >> 6, din0 = (blockIdx.x & 63) << 2;
    int t = threadIdx.x;
    wv[t >> 6][t & 63] = Wv[((h << 8) + din0 + (t >> 6)) * 64 + (t & 63)];
    __syncthreads();
    float s[4] = {0.f, 0.f, 0.f, 0.f};
    for (int a = 0; a < 64; ++a) {
        float wo = Wout[(h * 64 + a) * 256 + t];
        #pragma unroll
        for (int dd = 0; dd < 4; ++dd) s[dd] += wv[dd][a] * wo;
    }
    #pragma unroll
    for (int dd = 0; dd < 4; ++dd)
        CT[((long)t << 11) + (h << 8) + din0 + dd] = (_Float16)s[dd];
}

// ---------------- counting sort ----------------
__global__ void k_hist(const int* __restrict__ index, int* __restrict__ counts, int M) {
    int m = blockIdx.x * 256 + threadIdx.x;
    if (m < M) atomicAdd(&counts[index[m]], 1);
}

__global__ __launch_bounds__(1024) void k_scan1(const int* __restrict__ counts,
                                                int* __restrict__ starts,
                                                int* __restrict__ blocktot, int N) {
    __shared__ int s[1024];
    int b = blockIdx.x, t = threadIdx.x;
    int i = b * 1024 + t;
    int x = (i < N) ? counts[i] : 0;
    s[t] = x;
    __syncthreads();
    #pragma unroll
    for (int off = 1; off < 1024; off <<= 1) {
        int v = (t >= off) ? s[t - off] : 0;
        __syncthreads();
        s[t] += v;
        __syncthreads();
    }
    if (i < N) starts[i] = s[t] - x;
    if (t == 1023) blocktot[b] = s[1023];
}

__global__ void k_scan2(const int* __restrict__ blocktot, int* __restrict__ blockoff, int NC) {
    if (threadIdx.x == 0 && blockIdx.x == 0) {
        int run = 0;
        for (int i = 0; i < NC; ++i) { blockoff[i] = run; run += blocktot[i]; }
    }
}

__global__ __launch_bounds__(1024) void k_scan3(int* __restrict__ starts,
                                                int* __restrict__ cursor,
                                                const int* __restrict__ blockoff,
                                                int N, int M) {
    int b = blockIdx.x, t = threadIdx.x;
    int i = b * 1024 + t;
    if (i < N) {
        int v = starts[i] + blockoff[b];
        starts[i] = v;
        cursor[i] = v;
    }
    if (b == 0 && t == 0) starts[N] = M;
}

__global__ void k_scatteridx(const int* __restrict__ index, int* __restrict__ cursor,
                             int* __restrict__ sorted, int* __restrict__ segsorted, int M) {
    int m = blockIdx.x * 256 + threadIdx.x;
    if (m < M) {
        int idx = index[m];
        int pos = atomicAdd(&cursor[idx], 1);
        sorted[pos] = m;
        segsorted[pos] = idx;
    }
}

// ---------------- fused: q,k scores -> e; weighted msg segment-sum ----------------
__global__ __launch_bounds__(256, 3) void k_score_wsum(
    const float* __restrict__ msg, const int* __restrict__ sorted,
    const int* __restrict__ segsorted, const _Float16* __restrict__ wqkT,
    float* __restrict__ u, float* __restrict__ segsum, int M)
{
    __shared__ _Float16 At[64 * 256];   // 32 KB, XOR-swizzled
    __shared__ float e_lds[64][8];      // 2 KB
    __shared__ int s_id[64];
    __shared__ int s_sg[64];
    char* lds = (char*)At;
    const int t = threadIdx.x;

    // bijective XCD-chunked swizzle (neighbor blocks share boundary segs -> same L2)
    int nwg = gridDim.x;
    int qc = nwg >> 3, rc = nwg & 7;
    int xcd = blockIdx.x & 7, ofs = blockIdx.x >> 3;
    int b = ((xcd < rc) ? xcd * (qc + 1) : rc * (qc + 1) + (xcd - rc) * qc) + ofs;
    const long m0 = (long)b * 64;

    if (t < 64) {
        int sid = sorted[m0 + t];
        s_id[t] = sid;
        s_sg[t] = segsorted[m0 + t];
    }
    __syncthreads();

    // stage gathered 64x256 f32 -> f16 LDS
    const float4* msgf4 = (const float4*)msg;
    #pragma unroll
    for (int it = 0; it < 16; ++it) {
        int e4 = it * 256 + t;
        int row = e4 >> 6, c4 = e4 & 63;
        float4 v = msgf4[(long)s_id[row] * 64 + c4];
        half4 hv = {(_Float16)v.x, (_Float16)v.y, (_Float16)v.z, (_Float16)v.w};
        int bb = (row << 9) + (c4 << 3);
        bb ^= (row & 7) << 4;
        *(half4*)(lds + bb) = hv;
    }
    __syncthreads();

    const int w = t >> 6, l = t & 63, lr = l & 15, lk = l >> 4;
    const f32x4 zero = {0.f, 0.f, 0.f, 0.f};

    // ---- scores: wave w -> heads 2w, 2w+1; n-split-2 bounds VGPR ----
    #pragma unroll
    for (int hi = 0; hi < 2; ++hi) {
        const int h = w * 2 + hi;
        f32x4 p[4] = {zero, zero, zero, zero};
        #pragma unroll
        for (int nh = 0; nh < 2; ++nh) {
            f32x4 aq[2][4], ak[2][4];
            #pragma unroll
            for (int n2 = 0; n2 < 2; ++n2)
                #pragma unroll
                for (int r = 0; r < 4; ++r) { aq[n2][r] = zero; ak[n2][r] = zero; }
            #pragma unroll
            for (int k0 = 0; k0 < 8; ++k0) {
                half8 a[4];
                #pragma unroll
                for (int r = 0; r < 4; ++r) {
                    int row = r * 16 + lr;
                    int bb = (row << 9) + ((k0 * 32 + lk * 8) << 1);
                    bb ^= (row & 7) << 4;
                    a[r] = *(const half8*)(lds + bb);
                }
                #pragma unroll
                for (int n2 = 0; n2 < 2; ++n2) {
                    int n = nh * 2 + n2;
                    half8 bq = *(const half8*)(wqkT + ((h * 64 + n * 16 + lr) << 8) + k0 * 32 + lk * 8);
                    half8 bk = *(const half8*)(wqkT + (((8 + h) * 64 + n * 16 + lr) << 8) + k0 * 32 + lk * 8);
                    #pragma unroll
                    for (int r = 0; r < 4; ++r) {
                        aq[n2][r] = __builtin_amdgcn_mfma_f32_16x16x32_f16(a[r], bq, aq[n2][r], 0, 0, 0);
                        ak[n2][r] = __builtin_amdgcn_mfma_f32_16x16x32_f16(a[r], bk, ak[n2][r], 0, 0, 0);
                    }
                }
            }
            #pragma unroll
            for (int n2 = 0; n2 < 2; ++n2)
                #pragma unroll
                for (int r = 0; r < 4; ++r)
                    p[r] += aq[n2][r] * ak[n2][r];
        }
        #pragma unroll
        for (int off = 1; off < 16; off <<= 1) {
            #pragma unroll
            for (int r = 0; r < 4; ++r) {
                p[r][0] += __shfl_xor(p[r][0], off);
                p[r][1] += __shfl_xor(p[r][1], off);
                p[r][2] += __shfl_xor(p[r][2], off);
                p[r][3] += __shfl_xor(p[r][3], off);
            }
        }
        if (lr == 0) {
            #pragma unroll
            for (int r = 0; r < 4; ++r) {
                #pragma unroll
                for (int j = 0; j < 4; ++j) {
                    float s = p[r][j];
                    s = (s >= 0.f) ? s : 0.2f * s;
                    e_lds[r * 16 + lk * 4 + j][h] = __expf(s);  // |s|<~45 << 88: f32-safe
                }
            }
        }
    }
    __syncthreads();

    // ---- weighted segment-sum: wave w accumulates heads 2w,2w+1; lane owns 4 cols ----
    const int gl0 = s_sg[0], ghi = s_sg[63];
    const int h0 = w * 2, h1 = h0 + 1;
    float a0[4] = {0.f, 0.f, 0.f, 0.f}, a1[4] = {0.f, 0.f, 0.f, 0.f};
    float se0 = 0.f, se1 = 0.f;
    int cur = gl0;

    auto flush = [&](int g) {
        bool bd = (g == gl0) || (g == ghi);
        float* d0 = u + (long)g * 2048 + h0 * 256 + l * 4;
        float* d1 = u + (long)g * 2048 + h1 * 256 + l * 4;
        if (bd) {
            #pragma unroll
            for (int j = 0; j < 4; ++j) { atomicAdd(d0 + j, a0[j]); atomicAdd(d1 + j, a1[j]); }
        } else {
            float4 v0 = {a0[0], a0[1], a0[2], a0[3]};
            float4 v1 = {a1[0], a1[1], a1[2], a1[3]};
            *(float4*)d0 = v0;
            *(float4*)d1 = v1;
        }
        if (l == 0) {
            float* ds = segsum + (long)g * 8;
            if (bd) { atomicAdd(ds + h0, se0); atomicAdd(ds + h1, se1); }
            else { ds[h0] = se0; ds[h1] = se1; }
        }
    };

    #pragma unroll 4
    for (int row = 0; row < 64; ++row) {
        int sg = s_sg[row];
        if (sg != cur) {            // wave-uniform branch
            flush(cur);
            cur = sg;
            #pragma unroll
            for (int j = 0; j < 4; ++j) { a0[j] = 0.f; a1[j] = 0.f; }
            se0 = 0.f; se1 = 0.f;
        }
        int bb = ((row << 9) + (l << 3)) ^ ((row & 7) << 4);
        half4 mv = *(const half4*)(lds + bb);
        float e0 = e_lds[row][h0], e1 = e_lds[row][h1];
        #pragma unroll
        for (int j = 0; j < 4; ++j) {
            float mf = (float)mv[j];
            a0[j] += e0 * mf;
            a1[j] += e1 * mf;
        }
        if (l == 0) { se0 += e0; se1 += e1; }
    }
    flush(cur);
}

// ---------------- out = (u/segsum) @ CT^T + bout   (K=2048, chunk==head) ----------------
__global__ __launch_bounds__(256) void k_out2(
    const float* __restrict__ u, const float* __restrict__ segsum,
    const _Float16* __restrict__ CT, const float* __restrict__ bout,
    float* __restrict__ out, int N)
{
    __shared__ _Float16 At[64 * 256];   // 32 KB swizzled, per k-chunk
    char* lds = (char*)At;
    const int t = threadIdx.x;
    const long n0 = (long)blockIdx.x * 64;
    const int w = t >> 6, l = t & 63, lr = l & 15, lk = l >> 4;
    const f32x4 zero = {0.f, 0.f, 0.f, 0.f};

    f32x4 ac[4][4];
    #pragma unroll
    for (int r = 0; r < 4; ++r)
        #pragma unroll
        for (int n = 0; n < 4; ++n) ac[r][n] = zero;

    #pragma unroll 1
    for (int kc = 0; kc < 8; ++kc) {    // k-chunk == head
        __syncthreads();
        #pragma unroll
        for (int it = 0; it < 16; ++it) {
            int e4 = it * 256 + t;
            int row = e4 >> 6, c4 = e4 & 63;
            long gr = n0 + row;
            float4 v = {0.f, 0.f, 0.f, 0.f};
            float inv = 0.f;
            if (gr < N) {
                v = ((const float4*)u)[gr * 512 + kc * 64 + c4];
                float ss = segsum[gr * 8 + kc];
                inv = (ss > 0.f) ? 1.f / ss : 0.f;
            }
            half4 hv = {(_Float16)(v.x * inv), (_Float16)(v.y * inv),
                        (_Float16)(v.z * inv), (_Float16)(v.w * inv)};
            int bb = (row << 9) + (c4 << 3);
            bb ^= (row & 7) << 4;
            *(half4*)(lds + bb) = hv;
        }
        __syncthreads();
        #pragma unroll
        for (int k0 = 0; k0 < 8; ++k0) {
            half8 a[4];
            #pragma unroll
            for (int r = 0; r < 4; ++r) {
                int row = r * 16 + lr;
                int bb = (row << 9) + ((k0 * 32 + lk * 8) << 1);
                bb ^= (row & 7) << 4;
                a[r] = *(const half8*)(lds + bb);
            }
            #pragma unroll
            for (int n = 0; n < 4; ++n) {
                half8 bw = *(const half8*)(CT + ((long)(w * 64 + n * 16 + lr) << 11)
                                              + kc * 256 + k0 * 32 + lk * 8);
                #pragma unroll
                for (int r = 0; r < 4; ++r)
                    ac[r][n] = __builtin_amdgcn_mfma_f32_16x16x32_f16(a[r], bw, ac[r][n], 0, 0, 0);
            }
        }
    }
    #pragma unroll
    for (int n = 0; n < 4; ++n) {
        int col = w * 64 + n * 16 + lr;
        float bb = bout[col];
        #pragma unroll
        for (int r = 0; r < 4; ++r) {
            #pragma unroll
            for (int j = 0; j < 4; ++j) {
                long row = n0 + r * 16 + lk * 4 + j;
                if (row < N) out[row * 256 + col] = ac[r][n][j] + bb;
            }
        }
    }
}

extern "C" void kernel_launch(void* const* d_in, const int* in_sizes, int n_in,
                              void* d_out, int out_size, void* d_ws, size_t ws_size,
                              hipStream_t stream)
{
    const float* msg   = (const float*)d_in[0];
    const int*   index = (const int*)d_in[1];
    const float* Wq    = (const float*)d_in[4];
    const float* Wk    = (const float*)d_in[5];
    const float* Wv    = (const float*)d_in[6];
    const float* Wout  = (const float*)d_in[7];
    const float* bout  = (const float*)d_in[8];
    float* out = (float*)d_out;

    const int M = in_sizes[0] / 256;   // 400000
    const int N = out_size / 256;      // 50000
    const int NC = (N + 1023) / 1024;  // 49 scan chunks

    char* ws = (char*)d_ws;
    _Float16* wqkT = (_Float16*)(ws);              // 524288 B
    _Float16* CT   = (_Float16*)(ws + 524288);     // 1048576 B
    size_t o2 = 1572864;
    float* segsum = (float*)(ws + o2);                         // N*32
    int* counts   = (int*)(ws + o2 + (size_t)N * 32);          // N*4
    size_t uoff   = (o2 + (size_t)N * 36 + 255) & ~(size_t)255;
    float* u      = (float*)(ws + uoff);                       // N*8192
    size_t p2     = uoff + (size_t)N * 8192;
    int* cursor    = (int*)(ws + p2);                          // N*4
    int* starts    = (int*)(ws + p2 + (size_t)N * 4);          // (N+1)*4
    char* p3       = ws + p2 + (((size_t)N * 8 + 4 + 63) & ~(size_t)63);
    int* sorted    = (int*)(p3);                               // M*4
    int* segsorted = (int*)(p3 + (size_t)M * 4);               // M*4
    int* blocktot  = (int*)(p3 + (size_t)M * 8);               // 256 B
    int* blockoff  = (int*)(p3 + (size_t)M * 8 + 256);         // 256 B

    // zero segsum + counts + u (contiguous region)
    hipMemsetAsync(ws + o2, 0, p2 - o2, stream);

    k_convert<<<512, 256, 0, stream>>>(Wq, Wk, wqkT);
    k_convC<<<512, 256, 0, stream>>>(Wv, Wout, CT);
    k_hist<<<(M + 255) / 256, 256, 0, stream>>>(index, counts, M);
    k_scan1<<<NC, 1024, 0, stream>>>(counts, starts, blocktot, N);
    k_scan2<<<1, 64, 0, stream>>>(blocktot, blockoff, NC);
    k_scan3<<<NC, 1024, 0, stream>>>(starts, cursor, blockoff, N, M);
    k_scatteridx<<<(M + 255) / 256, 256, 0, stream>>>(index, cursor, sorted, segsorted, M);
    k_score_wsum<<<M / 64, 256, 0, stream>>>(msg, sorted, segsorted, wqkT, u, segsum, M);
    k_out2<<<(N + 63) / 64, 256, 0, stream>>>(u, segsum, CT, bout, out, N);
}